// Round 20
// baseline (341.427 us; speedup 1.0000x reference)
//
#include <hip/hip_runtime.h>

#define I_DIM 17
#define H_DIM 128
#define T_DIM 19
#define B_DIM 32768
#define M_ROWS 64
#define NTHR 512
#define GRID (B_DIM / M_ROWS) /* 512 blocks -> 2 resident per CU */
#define XI 323
#define NF (M_ROWS * XI)      /* 20672 */
#define XSLOT 2176            /* per-t x: 2 rowgrp x 1024B + 128B k16 plane */

#define OFF_H 0               /* 2 x 16384 (64 rows x 256B, full-16 swizzle) */
#define OFF_X 32768           /* 19 x 2176 = 41344 */
#define LDS_TOT 74112

/* d_ws fragment table (bytes): prescaled bf16 MFMA frags */
#define WS_WHH 0              /* [ct16][kk8][lane64]x16B = 131072 */
#define WS_WIH 131072         /* [ct16][f2][lane64]x16B  =  32768 */
#define WS_WO  163840         /* [yct2][kk4][lane64]x16B =   8192 */
#define WS_BYTES 172032

typedef __bf16 bf16x8 __attribute__((ext_vector_type(8)));
typedef float f32x4 __attribute__((ext_vector_type(4)));
typedef float f32x16 __attribute__((ext_vector_type(16)));
typedef float f32x4u __attribute__((ext_vector_type(4), aligned(4)));
union FragU { bf16x8 v; unsigned short s[8]; uint4 u; };

#define K1 1.4426950408889634f
#define K2 2.8853900817779268f

__device__ __forceinline__ unsigned short f2bf(float f) {
    union { float f; unsigned u; } x; x.f = f;
    return (unsigned short)((x.u + 0x8000u) >> 16);
}

/* ---------------- pre-pass: build prescaled bf16 frags in d_ws ---------------- */
__global__ __launch_bounds__(256) void prep(
    const float* __restrict__ W_ih, const float* __restrict__ W_hh,
    const float* __restrict__ b_ih, const float* __restrict__ b_hh,
    const float* __restrict__ W_out, unsigned char* __restrict__ ws)
{
    int idx = blockIdx.x * 256 + threadIdx.x;   /* 0..10751 */
    if (idx >= 10752) return;
    int lane = idx & 63, fid = idx >> 6;        /* fid 0..167 */
    FragU fu; fu.u = (uint4){0u, 0u, 0u, 0u};
    if (fid < 128) {                            /* whh: ct=fid>>3, kk=fid&7 */
        int kk = fid & 7, ct = fid >> 3;
        int l31 = lane & 31, hi = lane >> 5;
        int jrow = l31 & 7, grow = l31 >> 3;
        float sc = (grow == 2) ? -K2 : -K1;
        int n = grow * H_DIM + ct * 8 + jrow;
        const float* sp = W_hh + n * H_DIM + kk * 16 + hi * 8;
        #pragma unroll
        for (int e = 0; e < 8; ++e) fu.s[e] = f2bf(sp[e] * sc);
    } else if (fid < 160) {                     /* wih: ct=(fid-128)>>1, f=(fid-128)&1 */
        int rel = fid - 128, fi = rel & 1, ct = rel >> 1;
        int l31 = lane & 31, hi = lane >> 5;
        int jrow = l31 & 7, grow = l31 >> 3;
        float sc = (grow == 2) ? -K2 : -K1;
        int n = grow * H_DIM + ct * 8 + jrow;
        if (fi == 0) {
            #pragma unroll
            for (int e = 0; e < 8; ++e)
                fu.s[e] = f2bf(W_ih[n * I_DIM + hi * 8 + e] * sc);
        } else {
            #pragma unroll
            for (int e = 0; e < 8; ++e) {
                int k1 = 16 + hi * 8 + e;
                float v = 0.f;
                if (k1 == 16)      v = W_ih[n * I_DIM + 16] * sc;
                else if (k1 == 17) v = (b_ih[n] + b_hh[n]) * sc;
                fu.s[e] = f2bf(v);
            }
        }
    } else {                                    /* wo: yct=(fid-160)>>2, kk=(fid-160)&3 */
        int rel = fid - 160, kk = rel & 3, yct = rel >> 2;
        int l15 = lane & 15, q = lane >> 4;
        int o = yct * 16 + l15, kb = kk * 32 + q * 8;
        #pragma unroll
        for (int e = 0; e < 8; ++e)
            fu.s[e] = (o < I_DIM) ? f2bf(W_out[o * H_DIM + kb + e]) : (unsigned short)0;
    }
    *(uint4*)(ws + (size_t)idx * 16) = fu.u;
}

/* ---------------- main kernel macros ---------------- */

/* hb: 4 h B-frags (K-chunks HALF*4..+3) for batch-tile BT from H[1-P] */
#define RB4(BT_, HALF_, P_) do {                                                  \
    _Pragma("unroll") for (int kk = 0; kk < 4; ++kk)                              \
        hb[kk] = *(const bf16x8*)(smem + OFF_H + (1 - (P_)) * 16384               \
                 + ((BT_) * 32 + l31) * 256                                       \
                 + (((((HALF_) * 4 + kk) * 32) + hi * 16) ^ sw15));               \
} while (0)

/* x-projection init (2 MFMAs, bias folded at k17) */
#define MQX(ACC_, BT_, WI0_, WI1_) do {                                           \
    FragU f1; f1.v = *(const bf16x8*)(smem + xt + (BT_) * 1024 + lane * 16);      \
    FragU f2; f2.u = (uint4){0u, 0u, 0u, 0u};                                     \
    if (hi == 0) {                                                                \
        f2.s[0] = *(const unsigned short*)(smem + xt + 2048 + ((BT_) * 32 + l31) * 2); \
        f2.s[1] = (unsigned short)0x3F80;                                         \
    }                                                                             \
    f32x16 z = {0.f,0.f,0.f,0.f,0.f,0.f,0.f,0.f,0.f,0.f,0.f,0.f,0.f,0.f,0.f,0.f};\
    ACC_ = __builtin_amdgcn_mfma_f32_32x32x16_bf16(WI0_, f1.v, z, 0, 0, 0);       \
    ACC_ = __builtin_amdgcn_mfma_f32_32x32x16_bf16(WI1_, f2.v, ACC_, 0, 0, 0);    \
} while (0)

/* load 4 whh A-frags (K-chunks KLO..+3) for col-tile CT from d_ws */
#define LDW(CT_, KLO_) do {                                                       \
    _Pragma("unroll") for (int kk = 0; kk < 4; ++kk)                              \
        wa[kk] = *(const bf16x8*)(wsb + WS_WHH + ((CT_) * 8 + (KLO_) + kk) * 1024 + lane * 16); \
} while (0)

#define MQH(ACC_) do {                                                            \
    _Pragma("unroll") for (int kk = 0; kk < 4; ++kk)                              \
        ACC_ = __builtin_amdgcn_mfma_f32_32x32x16_bf16(wa[kk], hb[kk], ACC_, 0, 0, 0); \
} while (0)

/* elementwise: 4 i/f/g/o quadruples/lane; b64 h-write into H[P] */
#define EQ(ACC_, TI_, CTI_, BT_, P_) do {                                         \
    unsigned long long hp = 0ull;                                                 \
    _Pragma("unroll") for (int jj = 0; jj < 4; ++jj) {                            \
        float ui = __builtin_amdgcn_exp2f(ACC_[jj]);                              \
        float uf = __builtin_amdgcn_exp2f(ACC_[4 + jj]);                          \
        float vg = __builtin_amdgcn_exp2f(ACC_[8 + jj]);                          \
        float uo = __builtin_amdgcn_exp2f(ACC_[12 + jj]);                         \
        float A_ = 1.f + ui, F_ = 1.f + uf, G_ = 1.f + vg;                        \
        float AG = A_ * G_;                                                       \
        int ci = (TI_) * 4 + jj;                                                  \
        float c = (cst[ci] * AG + (1.f - vg) * F_) * __builtin_amdgcn_rcpf(F_ * AG); \
        cst[ci] = c;                                                              \
        float vc = __builtin_amdgcn_exp2f(-K2 * c);                               \
        float h = (1.f - vc) * __builtin_amdgcn_rcpf((1.f + uo) * (1.f + vc));    \
        union { float f; unsigned u; } hu; hu.f = h;                              \
        hp |= (unsigned long long)((hu.u + 0x8000u) >> 16) << (16 * jj);          \
    }                                                                             \
    *(unsigned long long*)(smem + OFF_H + (P_) * 16384 + ((BT_) * 32 + l31) * 256 \
        + (((2 * w + (CTI_)) * 16 + hi * 8) ^ sw15)) = hp;                        \
} while (0)

/* y_{t-1}: one 16x16 tile per wave; wo frags from d_ws; reads H[1-P] */
#define YB(P_) do {                                                               \
    f32x4 ya = {0.f, 0.f, 0.f, 0.f};                                              \
    _Pragma("unroll") for (int kk = 0; kk < 4; ++kk) {                            \
        bf16x8 wo_ = *(const bf16x8*)(wsb + WS_WO + (yct * 4 + kk) * 1024 + lane * 16); \
        bf16x8 h0 = *(const bf16x8*)(smem + OFF_H + (1 - (P_)) * 16384            \
                   + (ybt * 16 + l15) * 256 + ((kk * 64 + q * 16) ^ (l15 << 4))); \
        ya = __builtin_amdgcn_mfma_f32_16x16x32_bf16(wo_, h0, ya, 0, 0, 0);       \
    }                                                                             \
    if (yct == 0) { *(f32x4u*)ypt = ya + ybo; }                                   \
    else if (q == 0) { ypt[0] = ya[0] + ybo[0]; }                                 \
    ypt += I_DIM;                                                                 \
} while (0)

/* one ct (2 batch tiles, acc A/B); whh streamed in 2 half-K rounds */
#define CTBODY(CTI_, TI0_, P_, REC_) do {                                         \
    bf16x8 hb[4], wa[4];                                                          \
    bf16x8 wi0 = *(const bf16x8*)(wsb + WS_WIH + (2 * w + (CTI_)) * 2048 + lane * 16); \
    bf16x8 wi1 = *(const bf16x8*)(wsb + WS_WIH + (2 * w + (CTI_)) * 2048 + 1024 + lane * 16); \
    MQX(accA, 0, wi0, wi1);                                                       \
    MQX(accB, 1, wi0, wi1);                                                       \
    if (REC_) {                                                                   \
        LDW(2 * w + (CTI_), 0);                                                   \
        RB4(0, 0, P_); MQH(accA);                                                 \
        RB4(1, 0, P_); MQH(accB);                                                 \
        LDW(2 * w + (CTI_), 4);                                                   \
        RB4(0, 1, P_); MQH(accA);                                                 \
        RB4(1, 1, P_); MQH(accB);                                                 \
    }                                                                             \
    EQ(accA, (TI0_), CTI_, 0, P_);                                                \
    EQ(accB, (TI0_) + 1, CTI_, 1, P_);                                            \
} while (0)

#define STEP(P_, REC_) do {                                                       \
    CTBODY(0, 0, P_, REC_);                                                       \
    if (REC_) YB(P_);                                                             \
    CTBODY(1, 2, P_, REC_);                                                       \
    xt += XSLOT;                                                                  \
    __syncthreads();                                                              \
} while (0)

__global__ __launch_bounds__(NTHR)
__attribute__((amdgpu_waves_per_eu(4, 4)))
void flowlstm(
    const float* __restrict__ x, const float* __restrict__ b_out,
    const unsigned char* __restrict__ wsb, float* __restrict__ out)
{
    __shared__ __align__(16) unsigned char smem[LDS_TOT];
    const int tid = threadIdx.x;
    const int w = tid >> 6, lane = tid & 63;
    const int l31 = lane & 31, hi = lane >> 5, l15 = lane & 15, q = lane >> 4;
    const unsigned sw15 = (unsigned)((l31 & 15) << 4);
    const int b0 = blockIdx.x * M_ROWS;

    /* ---- bulk x stage: coalesced dwords -> 32-wide frag layout + k16 plane ---- */
    {
        const float* xb = x + (size_t)b0 * XI;
        for (int j = 0; j < 41; ++j) {
            int f = tid + j * NTHR;
            if (f < NF) {
                float v = xb[f];
                unsigned uf_ = (unsigned)f;
                unsigned row = (uf_ * 51943u) >> 24;      /* f / 323 */
                unsigned s = uf_ - row * 323u;
                unsigned t = (s * 61681u) >> 20;          /* s / 17 */
                unsigned k = s - t * 17u;
                unsigned a;
                if (k == 16u)
                    a = OFF_X + t * XSLOT + 2048 + row * 2;
                else
                    a = OFF_X + t * XSLOT + (row >> 5) * 1024
                      + (((k >> 3) * 32 + (row & 31)) * 16) + (k & 7) * 2;
                *(unsigned short*)(smem + a) = f2bf(v);
            }
        }
    }
    /* ---- y constants ---- */
    const int ybt = w >> 1, yct = w & 1;
    f32x4 ybo;
    #pragma unroll
    for (int r = 0; r < 4; ++r) {
        int col = yct * 16 + 4 * q + r;
        ybo[r] = b_out[col < I_DIM ? col : 16];
    }
    float* ypt = out + (size_t)(b0 + ybt * 16 + l15) * XI + (yct ? 16 : 4 * q);

    float cst[16];
    #pragma unroll
    for (int i = 0; i < 16; ++i) cst[i] = 0.f;
    f32x16 accA, accB;
    unsigned xt = OFF_X;

    __syncthreads();   /* x staging visible */

    /* t=0 peel: x-proj only, writes H[0] */
    STEP(0, 0);
    /* t = 1..18 */
    #pragma unroll 1
    for (int t = 1; t < T_DIM; t += 2) {
        STEP(1, 1);
        STEP(0, 1);
    }
    /* epilogue: y_18 from H[0] */
    YB(1);
}

extern "C" void kernel_launch(void* const* d_in, const int* in_sizes, int n_in,
                              void* d_out, int out_size, void* d_ws, size_t ws_size,
                              hipStream_t stream) {
    const float* x     = (const float*)d_in[0];
    const float* W_ih  = (const float*)d_in[1];
    const float* W_hh  = (const float*)d_in[2];
    const float* b_ih  = (const float*)d_in[3];
    const float* b_hh  = (const float*)d_in[4];
    const float* W_out = (const float*)d_in[5];
    const float* b_out = (const float*)d_in[6];
    float* out = (float*)d_out;
    unsigned char* ws = (unsigned char*)d_ws;

    prep<<<dim3(42), dim3(256), 0, stream>>>(W_ih, W_hh, b_ih, b_hh, W_out, ws);
    flowlstm<<<dim3(GRID), dim3(NTHR), 0, stream>>>(x, b_out, ws, out);
}

// Round 21
// 147.636 us; speedup vs baseline: 2.3126x; 2.3126x over previous
//
#include <hip/hip_runtime.h>

#define I_DIM 17
#define H_DIM 128
#define T_DIM 19
#define B_DIM 32768
#define M_ROWS 64
#define NTHR 1024
#define GRID (B_DIM / M_ROWS) /* 512 blocks, 1/CU, 2 passes */
#define XI 323
#define NF (M_ROWS * XI)      /* 20672 */
#define XSLOT 2176            /* per-t x: 2 rowgrp x 1024B + 128B k16 plane */

#define OFF_H 0               /* 2 x 16384 (64 rows x 256B, full-16 swizzle) */
#define OFF_X 32768           /* 19 x 2176 = 41344 */
#define OFF_WO 74112          /* 8 frags x 1024 = 8192 */
#define LDS_TOT 82304

typedef __bf16 bf16x8 __attribute__((ext_vector_type(8)));
typedef float f32x4 __attribute__((ext_vector_type(4)));
typedef float f32x16 __attribute__((ext_vector_type(16)));
typedef float f32x4u __attribute__((ext_vector_type(4), aligned(4)));
union FragU { bf16x8 v; unsigned short s[8]; uint4 u; };

#define K1 1.4426950408889634f
#define K2 2.8853900817779268f

__device__ __forceinline__ unsigned short f2bf(float f) {
    union { float f; unsigned u; } x; x.f = f;
    return (unsigned short)((x.u + 0x8000u) >> 16);
}

/* hb: 4 h B-frags (K-chunks HALF*4..+3) for batch-tile BT from H[1-P] */
#define RB4(BT_, HALF_, P_) do {                                                  \
    _Pragma("unroll") for (int kk = 0; kk < 4; ++kk)                              \
        hb[kk] = *(const bf16x8*)(smem + OFF_H + (1 - (P_)) * 16384               \
                 + ((BT_) * 32 + l31) * 256                                       \
                 + (((((HALF_) * 4 + kk) * 32) + hi * 16) ^ sw15));               \
} while (0)

/* x-projection init (2 MFMAs, bias folded at k17) */
#define MQX(ACC_, BT_) do {                                                       \
    FragU f1; f1.v = *(const bf16x8*)(smem + xt + (BT_) * 1024 + lane * 16);      \
    FragU f2; f2.u = (uint4){0u, 0u, 0u, 0u};                                     \
    if (hi == 0) {                                                                \
        f2.s[0] = *(const unsigned short*)(smem + xt + 2048 + ((BT_) * 32 + l31) * 2); \
        f2.s[1] = (unsigned short)0x3F80;                                         \
    }                                                                             \
    f32x16 z = {0.f,0.f,0.f,0.f,0.f,0.f,0.f,0.f,0.f,0.f,0.f,0.f,0.f,0.f,0.f,0.f};\
    ACC_ = __builtin_amdgcn_mfma_f32_32x32x16_bf16(wi0r, f1.v, z, 0, 0, 0);       \
    ACC_ = __builtin_amdgcn_mfma_f32_32x32x16_bf16(wi1r, f2.v, ACC_, 0, 0, 0);    \
} while (0)

/* 4 recurrent MFMAs: whh K-chunks KLO..+3 x hb[0..3] */
#define MQH(ACC_, KLO_) do {                                                      \
    _Pragma("unroll") for (int kk = 0; kk < 4; ++kk)                              \
        ACC_ = __builtin_amdgcn_mfma_f32_32x32x16_bf16(whh[(KLO_) + kk], hb[kk], ACC_, 0, 0, 0); \
} while (0)

/* elementwise: 4 i/f/g/o quadruples/lane; b64 h-write into H[P] */
#define EQ(ACC_, BT_, P_) do {                                                    \
    unsigned long long hp = 0ull;                                                 \
    _Pragma("unroll") for (int jj = 0; jj < 4; ++jj) {                            \
        float ui = __builtin_amdgcn_exp2f(ACC_[jj]);                              \
        float uf = __builtin_amdgcn_exp2f(ACC_[4 + jj]);                          \
        float vg = __builtin_amdgcn_exp2f(ACC_[8 + jj]);                          \
        float uo = __builtin_amdgcn_exp2f(ACC_[12 + jj]);                         \
        float A_ = 1.f + ui, F_ = 1.f + uf, G_ = 1.f + vg;                        \
        float AG = A_ * G_;                                                       \
        int ci = (BT_) * 4 + jj;                                                  \
        float c = (cst[ci] * AG + (1.f - vg) * F_) * __builtin_amdgcn_rcpf(F_ * AG); \
        cst[ci] = c;                                                              \
        float vc = __builtin_amdgcn_exp2f(-K2 * c);                               \
        float h = (1.f - vc) * __builtin_amdgcn_rcpf((1.f + uo) * (1.f + vc));    \
        union { float f; unsigned u; } hu; hu.f = h;                              \
        hp |= (unsigned long long)((hu.u + 0x8000u) >> 16) << (16 * jj);          \
    }                                                                             \
    *(unsigned long long*)(smem + OFF_H + (P_) * 16384 + ((BT_) * 32 + l31) * 256 \
        + ((w * 16 + hi * 8) ^ sw15)) = hp;                                       \
} while (0)

/* y_{t-1}: waves 0..7 one 16x16 tile each; wor from LDS; reads H[1-P] */
#define YB(P_) do {                                                               \
    f32x4 ya = {0.f, 0.f, 0.f, 0.f};                                              \
    _Pragma("unroll") for (int kk = 0; kk < 4; ++kk) {                            \
        bf16x8 wo_ = *(const bf16x8*)(smem + OFF_WO + (yct * 4 + kk) * 1024 + lane * 16); \
        bf16x8 h0 = *(const bf16x8*)(smem + OFF_H + (1 - (P_)) * 16384            \
                   + (ybt * 16 + l15) * 256 + ((kk * 64 + q * 16) ^ (l15 << 4))); \
        ya = __builtin_amdgcn_mfma_f32_16x16x32_bf16(wo_, h0, ya, 0, 0, 0);       \
    }                                                                             \
    if (yct == 0) { *(f32x4u*)ypt = ya + ybo; }                                   \
    else if (q == 0) { ypt[0] = ya[0] + ybo[0]; }                                 \
    ypt += I_DIM;                                                                 \
} while (0)

/* full step: wave owns ONE ct (8 packed h-cols); 2 batch tiles; 1 barrier */
#define STEP(P_, REC_) do {                                                       \
    bf16x8 hb[4];                                                                 \
    MQX(accA, 0);                                                                 \
    MQX(accB, 1);                                                                 \
    if (REC_) {                                                                   \
        RB4(0, 0, P_); MQH(accA, 0);                                              \
        RB4(1, 0, P_); MQH(accB, 0);                                              \
        RB4(0, 1, P_); MQH(accA, 4);                                              \
        RB4(1, 1, P_); MQH(accB, 4);                                              \
        if (w < 8) YB(P_);                                                        \
    }                                                                             \
    EQ(accA, 0, P_);                                                              \
    EQ(accB, 1, P_);                                                              \
    xt += XSLOT;                                                                  \
    __syncthreads();                                                              \
} while (0)

__global__ __launch_bounds__(NTHR)
__attribute__((amdgpu_waves_per_eu(4, 4)))
void flowlstm(
    const float* __restrict__ x, const float* __restrict__ W_ih,
    const float* __restrict__ W_hh, const float* __restrict__ b_ih,
    const float* __restrict__ b_hh, const float* __restrict__ W_out,
    const float* __restrict__ b_out, float* __restrict__ out)
{
    __shared__ __align__(16) unsigned char smem[LDS_TOT];
    const int tid = threadIdx.x;
    const int w = tid >> 6, lane = tid & 63;
    const int l31 = lane & 31, hi = lane >> 5, l15 = lane & 15, q = lane >> 4;
    const unsigned sw15 = (unsigned)((l31 & 15) << 4);
    const int b0 = blockIdx.x * M_ROWS;

    /* ---- bulk x stage: coalesced dwords -> 32-wide frag layout + k16 plane ---- */
    {
        const float* xb = x + (size_t)b0 * XI;
        for (int j = 0; j < 21; ++j) {
            int f = tid + j * NTHR;
            if (f < NF) {
                float v = xb[f];
                unsigned uf_ = (unsigned)f;
                unsigned row = (uf_ * 51943u) >> 24;      /* f / 323 */
                unsigned s = uf_ - row * 323u;
                unsigned t = (s * 61681u) >> 20;          /* s / 17 */
                unsigned k = s - t * 17u;
                unsigned a;
                if (k == 16u)
                    a = OFF_X + t * XSLOT + 2048 + row * 2;
                else
                    a = OFF_X + t * XSLOT + (row >> 5) * 1024
                      + (((k >> 3) * 32 + (row & 31)) * 16) + (k & 7) * 2;
                *(unsigned short*)(smem + a) = f2bf(v);
            }
        }
    }
    /* ---- W_out fragments -> LDS (8 frags: ct*4+kk, N pad 17->32) ---- */
    if (tid < 512) {
        int ln = tid & 63, f = tid >> 6;
        int kk = f & 3, ct = f >> 2;
        int o = ct * 16 + (ln & 15);
        int kb = kk * 32 + (ln >> 4) * 8;
        FragU fu;
        #pragma unroll
        for (int e = 0; e < 8; ++e)
            fu.s[e] = (o < I_DIM) ? f2bf(W_out[o * H_DIM + kb + e]) : (unsigned short)0;
        *(uint4*)(smem + OFF_WO + f * 1024 + ln * 16) = fu.u;
    }
    /* ---- whh A-frags in regs: wave owns ct=w (8 frags = 32 regs), PRE-SCALED ---- */
    const int jrow = l31 & 7, grow = l31 >> 3;
    const float scl = (grow == 2) ? -K2 : -K1;
    const int nrow = grow * H_DIM + w * 8 + jrow;
    bf16x8 whh[8];
    #pragma unroll
    for (int kk = 0; kk < 8; ++kk) {
        const float* sp = W_hh + nrow * H_DIM + kk * 16 + hi * 8;
        FragU fu;
        #pragma unroll
        for (int e = 0; e < 8; ++e) fu.s[e] = f2bf(sp[e] * scl);
        whh[kk] = fu.v;
    }
    /* ---- wihr A-frags (2): k0..15 and k16(x)/k17(bias)/pad ---- */
    bf16x8 wi0r, wi1r;
    {
        FragU fa, fb;
        #pragma unroll
        for (int e = 0; e < 8; ++e) {
            fa.s[e] = f2bf(W_ih[nrow * I_DIM + hi * 8 + e] * scl);
            int k1 = 16 + hi * 8 + e;
            float v = 0.f;
            if (k1 == 16)      v = W_ih[nrow * I_DIM + 16] * scl;
            else if (k1 == 17) v = (b_ih[nrow] + b_hh[nrow]) * scl;
            fb.s[e] = f2bf(v);
        }
        wi0r = fa.v;
        wi1r = fb.v;
    }
    /* ---- y constants (waves 0..7) ---- */
    const int ybt = w >> 1, yct = w & 1;
    f32x4 ybo;
    #pragma unroll
    for (int r = 0; r < 4; ++r) {
        int col = yct * 16 + 4 * q + r;
        ybo[r] = b_out[col < I_DIM ? col : 16];
    }
    float* ypt = out + (size_t)(b0 + ybt * 16 + l15) * XI + (yct ? 16 : 4 * q);

    float cst[8];
    #pragma unroll
    for (int i = 0; i < 8; ++i) cst[i] = 0.f;
    f32x16 accA, accB;
    unsigned xt = OFF_X;

    __syncthreads();   /* staging visible */

    /* t=0 peel: x-proj only, writes H[0] */
    STEP(0, 0);
    /* t = 1..18 */
    #pragma unroll 1
    for (int t = 1; t < T_DIM; t += 2) {
        STEP(1, 1);
        STEP(0, 1);
    }
    /* epilogue: y_18 from H[0] */
    if (w < 8) YB(1);
}

extern "C" void kernel_launch(void* const* d_in, const int* in_sizes, int n_in,
                              void* d_out, int out_size, void* d_ws, size_t ws_size,
                              hipStream_t stream) {
    const float* x     = (const float*)d_in[0];
    const float* W_ih  = (const float*)d_in[1];
    const float* W_hh  = (const float*)d_in[2];
    const float* b_ih  = (const float*)d_in[3];
    const float* b_hh  = (const float*)d_in[4];
    const float* W_out = (const float*)d_in[5];
    const float* b_out = (const float*)d_in[6];
    float* out = (float*)d_out;

    dim3 grid(GRID), block(NTHR);
    flowlstm<<<grid, block, 0, stream>>>(x, W_ih, W_hh, b_ih, b_hh, W_out, b_out, out);
}

// Round 22
// 140.950 us; speedup vs baseline: 2.4223x; 1.0474x over previous
//
#include <hip/hip_runtime.h>

#define I_DIM 17
#define H_DIM 128
#define T_DIM 19
#define B_DIM 32768
#define M_ROWS 64
#define NTHR 1024
#define GRID (B_DIM / M_ROWS) /* 512 blocks, 1/CU, 2 passes */
#define XI 323
#define NF (M_ROWS * XI)      /* 20672 */
#define XSLOT 2176            /* per-t x: 2 rowgrp x 1024B + 128B k16 plane */

#define OFF_H 0               /* 2 x 16384 (64 rows x 256B, full-16 swizzle) */
#define OFF_X 32768           /* 19 x 2176 = 41344 */
#define OFF_WO 74112          /* 8 frags x 1024 = 8192 */
#define LDS_TOT 82304

typedef __bf16 bf16x8 __attribute__((ext_vector_type(8)));
typedef float f32x4 __attribute__((ext_vector_type(4)));
typedef float f32x16 __attribute__((ext_vector_type(16)));
typedef float f32x4u __attribute__((ext_vector_type(4), aligned(4)));
union FragU { bf16x8 v; unsigned short s[8]; uint4 u; };

#define K1 1.4426950408889634f
#define K2 2.8853900817779268f

__device__ __forceinline__ unsigned short f2bf(float f) {
    union { float f; unsigned u; } x; x.f = f;
    return (unsigned short)((x.u + 0x8000u) >> 16);
}

/* hb: 4 h B-frags (K-chunks HALF*4..+3) for batch-tile BT from H[1-P] */
#define RB4(BT_, HALF_, P_) do {                                                  \
    _Pragma("unroll") for (int kk = 0; kk < 4; ++kk)                              \
        hb[kk] = *(const bf16x8*)(smem + OFF_H + (1 - (P_)) * 16384               \
                 + ((BT_) * 32 + l31) * 256                                       \
                 + (((((HALF_) * 4 + kk) * 32) + hi * 16) ^ sw15));               \
} while (0)

/* x-projection init (2 MFMAs, bias folded at k17) */
#define MQX(ACC_, BT_) do {                                                       \
    FragU f1; f1.v = *(const bf16x8*)(smem + xt + (BT_) * 1024 + lane * 16);      \
    FragU f2; f2.u = (uint4){0u, 0u, 0u, 0u};                                     \
    if (hi == 0) {                                                                \
        f2.s[0] = *(const unsigned short*)(smem + xt + 2048 + ((BT_) * 32 + l31) * 2); \
        f2.s[1] = (unsigned short)0x3F80;                                         \
    }                                                                             \
    f32x16 z = {0.f,0.f,0.f,0.f,0.f,0.f,0.f,0.f,0.f,0.f,0.f,0.f,0.f,0.f,0.f,0.f};\
    ACC_ = __builtin_amdgcn_mfma_f32_32x32x16_bf16(wi0r, f1.v, z, 0, 0, 0);       \
    ACC_ = __builtin_amdgcn_mfma_f32_32x32x16_bf16(wi1r, f2.v, ACC_, 0, 0, 0);    \
} while (0)

/* 4 recurrent MFMAs: whh K-chunks KLO..+3 x hb[0..3] */
#define MQH(ACC_, KLO_) do {                                                      \
    _Pragma("unroll") for (int kk = 0; kk < 4; ++kk)                              \
        ACC_ = __builtin_amdgcn_mfma_f32_32x32x16_bf16(whh[(KLO_) + kk], hb[kk], ACC_, 0, 0, 0); \
} while (0)

/* elementwise: 4 i/f/g/o quadruples/lane; b64 h-write into H[P] */
#define EQ(ACC_, BT_, P_) do {                                                    \
    unsigned long long hp = 0ull;                                                 \
    _Pragma("unroll") for (int jj = 0; jj < 4; ++jj) {                            \
        float ui = __builtin_amdgcn_exp2f(ACC_[jj]);                              \
        float uf = __builtin_amdgcn_exp2f(ACC_[4 + jj]);                          \
        float vg = __builtin_amdgcn_exp2f(ACC_[8 + jj]);                          \
        float uo = __builtin_amdgcn_exp2f(ACC_[12 + jj]);                         \
        float A_ = 1.f + ui, F_ = 1.f + uf, G_ = 1.f + vg;                        \
        float AG = A_ * G_;                                                       \
        int ci = (BT_) * 4 + jj;                                                  \
        float c = (cst[ci] * AG + (1.f - vg) * F_) * __builtin_amdgcn_rcpf(F_ * AG); \
        cst[ci] = c;                                                              \
        float vc = __builtin_amdgcn_exp2f(-K2 * c);                               \
        float h = (1.f - vc) * __builtin_amdgcn_rcpf((1.f + uo) * (1.f + vc));    \
        union { float f; unsigned u; } hu; hu.f = h;                              \
        hp |= (unsigned long long)((hu.u + 0x8000u) >> 16) << (16 * jj);          \
    }                                                                             \
    *(unsigned long long*)(smem + OFF_H + (P_) * 16384 + ((BT_) * 32 + l31) * 256 \
        + ((w * 16 + hi * 8) ^ sw15)) = hp;                                       \
} while (0)

/* y_{t-1}: waves 0..7 one 16x16 tile each; wor from LDS; reads H[1-P] */
#define YB(P_) do {                                                               \
    f32x4 ya = {0.f, 0.f, 0.f, 0.f};                                              \
    _Pragma("unroll") for (int kk = 0; kk < 4; ++kk) {                            \
        bf16x8 wo_ = *(const bf16x8*)(smem + OFF_WO + (yct * 4 + kk) * 1024 + lane * 16); \
        bf16x8 h0 = *(const bf16x8*)(smem + OFF_H + (1 - (P_)) * 16384            \
                   + (ybt * 16 + l15) * 256 + ((kk * 64 + q * 16) ^ (l15 << 4))); \
        ya = __builtin_amdgcn_mfma_f32_16x16x32_bf16(wo_, h0, ya, 0, 0, 0);       \
    }                                                                             \
    if (yct == 0) { *(f32x4u*)ypt = ya + ybo; }                                   \
    else if (q == 0) { ypt[0] = ya[0] + ybo[0]; }                                 \
    ypt += I_DIM;                                                                 \
} while (0)

/* full step: wave owns ONE ct; SINGLE acc, serial per batch-tile; 1 barrier */
#define STEP(P_, REC_) do {                                                       \
    bf16x8 hb[4];                                                                 \
    MQX(acc, 0);                                                                  \
    if (REC_) {                                                                   \
        RB4(0, 0, P_); MQH(acc, 0);                                               \
        RB4(0, 1, P_); MQH(acc, 4);                                               \
    }                                                                             \
    EQ(acc, 0, P_);                                                               \
    MQX(acc, 1);                                                                  \
    if (REC_) {                                                                   \
        RB4(1, 0, P_); MQH(acc, 0);                                               \
        RB4(1, 1, P_); MQH(acc, 4);                                               \
        if (w < 8) YB(P_);                                                        \
    }                                                                             \
    EQ(acc, 1, P_);                                                               \
    xt += XSLOT;                                                                  \
    __syncthreads();                                                              \
} while (0)

__global__ __launch_bounds__(NTHR)
__attribute__((amdgpu_waves_per_eu(4, 4)))
void flowlstm(
    const float* __restrict__ x, const float* __restrict__ W_ih,
    const float* __restrict__ W_hh, const float* __restrict__ b_ih,
    const float* __restrict__ b_hh, const float* __restrict__ W_out,
    const float* __restrict__ b_out, float* __restrict__ out)
{
    __shared__ __align__(16) unsigned char smem[LDS_TOT];
    const int tid = threadIdx.x;
    const int w = tid >> 6, lane = tid & 63;
    const int l31 = lane & 31, hi = lane >> 5, l15 = lane & 15, q = lane >> 4;
    const unsigned sw15 = (unsigned)((l31 & 15) << 4);
    const int b0 = blockIdx.x * M_ROWS;

    /* ---- bulk x stage: coalesced dwords -> 32-wide frag layout + k16 plane ---- */
    {
        const float* xb = x + (size_t)b0 * XI;
        for (int j = 0; j < 21; ++j) {
            int f = tid + j * NTHR;
            if (f < NF) {
                float v = xb[f];
                unsigned uf_ = (unsigned)f;
                unsigned row = (uf_ * 51943u) >> 24;      /* f / 323 */
                unsigned s = uf_ - row * 323u;
                unsigned t = (s * 61681u) >> 20;          /* s / 17 */
                unsigned k = s - t * 17u;
                unsigned a;
                if (k == 16u)
                    a = OFF_X + t * XSLOT + 2048 + row * 2;
                else
                    a = OFF_X + t * XSLOT + (row >> 5) * 1024
                      + (((k >> 3) * 32 + (row & 31)) * 16) + (k & 7) * 2;
                *(unsigned short*)(smem + a) = f2bf(v);
            }
        }
    }
    /* ---- W_out fragments -> LDS (8 frags: ct*4+kk, N pad 17->32) ---- */
    if (tid < 512) {
        int ln = tid & 63, f = tid >> 6;
        int kk = f & 3, ct = f >> 2;
        int o = ct * 16 + (ln & 15);
        int kb = kk * 32 + (ln >> 4) * 8;
        FragU fu;
        #pragma unroll
        for (int e = 0; e < 8; ++e)
            fu.s[e] = (o < I_DIM) ? f2bf(W_out[o * H_DIM + kb + e]) : (unsigned short)0;
        *(uint4*)(smem + OFF_WO + f * 1024 + ln * 16) = fu.u;
    }
    /* ---- whh A-frags in regs: wave owns ct=w (8 frags = 32 regs), PRE-SCALED ---- */
    const int jrow = l31 & 7, grow = l31 >> 3;
    const float scl = (grow == 2) ? -K2 : -K1;
    const int nrow = grow * H_DIM + w * 8 + jrow;
    bf16x8 whh[8];
    #pragma unroll
    for (int kk = 0; kk < 8; ++kk) {
        const float* sp = W_hh + nrow * H_DIM + kk * 16 + hi * 8;
        FragU fu;
        #pragma unroll
        for (int e = 0; e < 8; ++e) fu.s[e] = f2bf(sp[e] * scl);
        whh[kk] = fu.v;
    }
    /* ---- wihr A-frags (2): k0..15 and k16(x)/k17(bias)/pad ---- */
    bf16x8 wi0r, wi1r;
    {
        FragU fa, fb;
        #pragma unroll
        for (int e = 0; e < 8; ++e) {
            fa.s[e] = f2bf(W_ih[nrow * I_DIM + hi * 8 + e] * scl);
            int k1 = 16 + hi * 8 + e;
            float v = 0.f;
            if (k1 == 16)      v = W_ih[nrow * I_DIM + 16] * scl;
            else if (k1 == 17) v = (b_ih[nrow] + b_hh[nrow]) * scl;
            fb.s[e] = f2bf(v);
        }
        wi0r = fa.v;
        wi1r = fb.v;
    }
    /* ---- y constants (waves 0..7) ---- */
    const int ybt = w >> 1, yct = w & 1;
    f32x4 ybo;
    #pragma unroll
    for (int r = 0; r < 4; ++r) {
        int col = yct * 16 + 4 * q + r;
        ybo[r] = b_out[col < I_DIM ? col : 16];
    }
    float* ypt = out + (size_t)(b0 + ybt * 16 + l15) * XI + (yct ? 16 : 4 * q);

    float cst[8];
    #pragma unroll
    for (int i = 0; i < 8; ++i) cst[i] = 0.f;
    f32x16 acc;
    unsigned xt = OFF_X;

    __syncthreads();   /* staging visible */

    /* t=0 peel: x-proj only, writes H[0] */
    STEP(0, 0);
    /* t = 1..18 */
    #pragma unroll 1
    for (int t = 1; t < T_DIM; t += 2) {
        STEP(1, 1);
        STEP(0, 1);
    }
    /* epilogue: y_18 from H[0] */
    if (w < 8) YB(1);
}

extern "C" void kernel_launch(void* const* d_in, const int* in_sizes, int n_in,
                              void* d_out, int out_size, void* d_ws, size_t ws_size,
                              hipStream_t stream) {
    const float* x     = (const float*)d_in[0];
    const float* W_ih  = (const float*)d_in[1];
    const float* W_hh  = (const float*)d_in[2];
    const float* b_ih  = (const float*)d_in[3];
    const float* b_hh  = (const float*)d_in[4];
    const float* W_out = (const float*)d_in[5];
    const float* b_out = (const float*)d_in[6];
    float* out = (float*)d_out;

    dim3 grid(GRID), block(NTHR);
    flowlstm<<<grid, block, 0, stream>>>(x, W_ih, W_hh, b_ih, b_hh, W_out, b_out, out);
}